// Round 15
// baseline (258.906 us; speedup 1.0000x reference)
//
#include <hip/hip_runtime.h>

#define FD 128
#define SHIFT 10         // nodes per bucket = 1024
#define BNODES 1024
#define NBK 128          // padded bucket-array size (98 used)
#define CHUNK 8192       // edges per scatter block
#define ST 512           // scatter block threads
#define NIT 16           // items per thread in scatter

typedef unsigned int u32;
typedef unsigned short u16;
typedef unsigned char u8;
typedef __attribute__((ext_vector_type(8))) short short8;   // 8 bf16 (4 VGPR)
typedef __attribute__((ext_vector_type(4))) float f32x4;
typedef __attribute__((ext_vector_type(4))) u32 u32x4;

__device__ inline u16 f2bf(float f) {            // fp32 -> bf16 RNE
  u32 u = __float_as_uint(f);
  u += 0x7fffu + ((u >> 16) & 1u);
  return (u16)(u >> 16);
}
__device__ inline float bf2f(u16 h) { return __uint_as_float((u32)h << 16); }

// ---------- pass 0: bucket histograms + W-prep in one launch ----------
__global__ __launch_bounds__(512) void k_histpw(
    const int* __restrict__ src, const int* __restrict__ dst,
    int* __restrict__ bcntD, int* __restrict__ bcntS, int e, int n, int nbuck,
    const float* __restrict__ W1, u32* __restrict__ wf1hi, u32* __restrict__ wf1lo,
    const float* __restrict__ W2, u32* __restrict__ wf2hi, u32* __restrict__ wf2lo) {
  int tid = threadIdx.x;
  if (blockIdx.x >= 256) {
    int gi = (blockIdx.x - 256) * 512 + tid;   // 0..16383
    int i = gi & 8191;
    const float* W = (gi < 8192) ? W1 : W2;
    u32* wfhi = (gi < 8192) ? wf1hi : wf2hi;
    u32* wflo = (gi < 8192) ? wf1lo : wf2lo;
    int m = i & 3, l = (i >> 2) & 63, f = i >> 8;
    int kt = f & 3, nt = f >> 2;
    int k0 = kt * 32 + ((l >> 4) << 3) + 2 * m;
    int c = nt * 16 + (l & 15);
    float w0 = W[k0 * FD + c], w1 = W[(k0 + 1) * FD + c];
    u16 h0 = f2bf(w0), h1 = f2bf(w1);
    u16 l0 = f2bf(w0 - bf2f(h0)), l1 = f2bf(w1 - bf2f(h1));
    wfhi[i] = (u32)h0 | ((u32)h1 << 16);
    wflo[i] = (u32)l0 | ((u32)l1 << 16);
    return;
  }
  __shared__ int shD[NBK];
  __shared__ int shS[NBK];
  if (tid < NBK) { shD[tid] = 0; shS[tid] = 0; }
  __syncthreads();
  int total = e + n;
  for (int t = blockIdx.x * 512 + tid; t < total; t += 256 * 512) {
    if (t < e) {
      atomicAdd(&shD[dst[t] >> SHIFT], 1);
      atomicAdd(&shS[src[t] >> SHIFT], 1);
    } else {
      atomicAdd(&shD[(t - e) >> SHIFT], 1);
    }
  }
  __syncthreads();
  if (tid < nbuck) {
    if (shD[tid]) atomicAdd(&bcntD[tid], shD[tid]);
    if (shS[tid]) atomicAdd(&bcntS[tid], shS[tid]);
  }
}

// ---------- pass 1: scan both bucket arrays ----------
__global__ __launch_bounds__(NBK) void k_bscan(
    const int* __restrict__ bcntD, const int* __restrict__ bcntS,
    int* __restrict__ bbaseD, int* __restrict__ bcurD,
    int* __restrict__ bbaseS, int* __restrict__ bcurS,
    int nbuck, int totalD, int totalS) {
  __shared__ int shD[NBK];
  __shared__ int shS[NBK];
  int tid = threadIdx.x;
  int vD = (tid < nbuck) ? bcntD[tid] : 0;
  int vS = (tid < nbuck) ? bcntS[tid] : 0;
  shD[tid] = vD; shS[tid] = vS;
  __syncthreads();
  for (int off = 1; off < NBK; off <<= 1) {
    int aD = (tid >= off) ? shD[tid - off] : 0;
    int aS = (tid >= off) ? shS[tid - off] : 0;
    __syncthreads();
    shD[tid] += aD; shS[tid] += aS;
    __syncthreads();
  }
  if (tid < nbuck) {
    int exD = shD[tid] - vD; bbaseD[tid] = exD; bcurD[tid] = exD;
    int exS = shS[tid] - vS; bbaseS[tid] = exS; bcurS[tid] = exS;
  }
  if (tid == 0) { bbaseD[nbuck] = totalD; bbaseS[nbuck] = totalS; }
}

// ---------- pass 2: scatter (blocks [0,nsc)) ∥ T1 = bf16(X@W1) (blocks [nsc,..)) ----------
// Scatter: CHUNK=8192, two-phase LDS staging (pairs then pairs2 reuse the arena).
__global__ __launch_bounds__(ST) void k_scatgx(
    const int* __restrict__ src, const int* __restrict__ dst,
    int* __restrict__ bcurD, int* __restrict__ bcurS,
    u32* __restrict__ pairs, u16* __restrict__ pairs2,
    int e, int n, int nbuck, int nsc,
    const float* __restrict__ x,
    const u32* __restrict__ wfhi, const u32* __restrict__ wflo,
    u32* __restrict__ tout) {
  __shared__ __align__(16) u8 smem[45056];   // 44 KB arena
  int tid512 = threadIdx.x;

  if (blockIdx.x >= (unsigned)nsc) {
    // ---- gemmx: two independent 64-row units (u = tid>>8) ----
    int u = tid512 >> 8, tid = tid512 & 255;
    u32* Au = (u32*)smem + u * 4096;   // 16 KB per unit
    int lane = tid & 63;
    int mt = tid >> 6;
    int r0 = ((blockIdx.x - nsc) * 2 + u) * 64;

    #pragma unroll
    for (int it = 0; it < 16; ++it) {
      int w = it * 256 + tid;
      int row = w >> 6, uu = w & 63;
      int grow = r0 + row;
      float2 v = make_float2(0.f, 0.f);
      if (grow < n) v = *(const float2*)(x + (size_t)grow * FD + uu * 2);
      Au[row * 64 + (uu ^ ((row & 7) << 2))] = (u32)f2bf(v.x) | ((u32)f2bf(v.y) << 16);
    }
    __syncthreads();

    short8 afh[4];
    int arow = mt * 16 + (lane & 15);
    #pragma unroll
    for (int kt = 0; kt < 4; ++kt) {
      int boff = arow * 256 + ((kt * 64 + (lane >> 4) * 16) ^ ((arow & 7) << 4));
      afh[kt] = *(const short8*)((const char*)Au + boff);
    }
    __syncthreads();   // Au dead -> epilogue staging

    for (int nt = 0; nt < 8; ++nt) {
      f32x4 oacc = {0.f, 0.f, 0.f, 0.f};
      #pragma unroll
      for (int kt = 0; kt < 4; ++kt) {
        int f = nt * 4 + kt;
        short8 wh = *(const short8*)(wfhi + (size_t)(f * 64 + lane) * 4);
        short8 wl = *(const short8*)(wflo + (size_t)(f * 64 + lane) * 4);
        oacc = __builtin_amdgcn_mfma_f32_16x16x32_bf16(afh[kt], wh, oacc, 0, 0, 0);
        oacc = __builtin_amdgcn_mfma_f32_16x16x32_bf16(afh[kt], wl, oacc, 0, 0, 0);
      }
      int c = nt * 16 + (lane & 15);
      #pragma unroll
      for (int j = 0; j < 4; ++j) {
        int lrow = mt * 16 + (lane >> 4) * 4 + j;
        ((u16*)Au)[lrow * 128 + c] = f2bf(oacc[j]);   // no bias, no scale
      }
    }
    __syncthreads();
    #pragma unroll
    for (int it = 0; it < 4; ++it) {
      int ci = it * 256 + tid;
      int lrow = ci >> 4, chk = ci & 15;
      int row = r0 + lrow;
      if (row < n)
        *(u32x4*)(tout + (size_t)row * 64 + chk * 4) =
            *(const u32x4*)(Au + lrow * 64 + chk * 4);
    }
    return;
  }

  // ---- scatter ----
  int* histD = (int*)smem;               // 8 x 128 ints = 4 KB
  int* exclD = histD + NBK;
  int* gbaseD = exclD + NBK;
  int* rankD = gbaseD + NBK;
  int* histS = rankD + NBK;
  int* exclS = histS + NBK;
  int* gbaseS = exclS + NBK;
  int* rankS = gbaseS + NBK;
  u32* stgv = (u32*)(smem + 4096);       // 32 KB (phase A)
  u8*  stgb = smem + 36864;              // 8 KB  (phase A)
  u16* stg2 = (u16*)(smem + 4096);       // 16 KB (phase B, reuses stgv)
  u8*  stg2b = smem + 20480;             // 8 KB  (phase B)
  int tid = tid512;
  int c0 = blockIdx.x * CHUNK;
  int total = e + n;
  if (tid < NBK) { histD[tid] = 0; histS[tid] = 0; }
  __syncthreads();
  u32 pv_[NIT]; int bD_[NIT], bS_[NIT]; bool v_[NIT], vs_[NIT];
  #pragma unroll
  for (int i = 0; i < NIT; ++i) {
    int t = c0 + i * ST + tid;
    v_[i] = (t < total);
    vs_[i] = (t < e);
    pv_[i] = 0; bD_[i] = 0; bS_[i] = 0;
    if (v_[i]) {
      int s, d;
      if (vs_[i]) { s = src[t]; d = dst[t]; }
      else        { s = t - e;  d = s; }
      pv_[i] = ((u32)(d & (BNODES - 1)) << 22) | (u32)s;
      bD_[i] = d >> SHIFT;
      atomicAdd(&histD[bD_[i]], 1);
      if (vs_[i]) { bS_[i] = s >> SHIFT; atomicAdd(&histS[bS_[i]], 1); }
    }
  }
  __syncthreads();
  int hD = 0, hS = 0;
  if (tid < NBK) { hD = histD[tid]; hS = histS[tid]; }
  __syncthreads();
  for (int off = 1; off < NBK; off <<= 1) {
    int aD = 0, aS = 0;
    if (tid < NBK && tid >= off) { aD = histD[tid - off]; aS = histS[tid - off]; }
    __syncthreads();
    if (tid < NBK) { histD[tid] += aD; histS[tid] += aS; }
    __syncthreads();
  }
  if (tid < NBK) {
    int exD = histD[tid] - hD; exclD[tid] = exD; rankD[tid] = exD;
    int exS = histS[tid] - hS; exclS[tid] = exS; rankS[tid] = exS;
    gbaseD[tid] = (tid < nbuck && hD > 0) ? atomicAdd(&bcurD[tid], hD) : 0;
    gbaseS[tid] = (tid < nbuck && hS > 0) ? atomicAdd(&bcurS[tid], hS) : 0;
  }
  __syncthreads();
  // phase A: dst-keyed pairs
  #pragma unroll
  for (int i = 0; i < NIT; ++i) {
    if (v_[i]) {
      int p = atomicAdd(&rankD[bD_[i]], 1);
      stgv[p] = pv_[i];
      stgb[p] = (u8)bD_[i];
    }
  }
  __syncthreads();
  int V = min(CHUNK, total - c0);
  for (int j = tid; j < V; j += ST) {
    int b = stgb[j];
    pairs[gbaseD[b] + (j - exclD[b])] = stgv[j];   // contiguous runs per bucket
  }
  __syncthreads();   // LDS reuse fence
  // phase B: src-keyed pairs2
  #pragma unroll
  for (int i = 0; i < NIT; ++i) {
    if (vs_[i]) {
      int p = atomicAdd(&rankS[bS_[i]], 1);
      stg2[p] = (u16)(pv_[i] & (BNODES - 1));   // local src id
      stg2b[p] = (u8)bS_[i];
    }
  }
  __syncthreads();
  int V2 = min(CHUNK, e - c0);                     // negative -> loop skipped
  for (int j = tid; j < V2; j += ST) {
    int b = stg2b[j];
    pairs2[gbaseS[b] + (j - exclS[b])] = stg2[j];
  }
}

// ---------- pass 3: merged per-bucket finalize (fast 2-level scan) ----------
__global__ __launch_bounds__(1024) void k_build(
    const u32* __restrict__ pairs, const int* __restrict__ bbase,
    const u16* __restrict__ pairs2, const int* __restrict__ bbaseS,
    int* __restrict__ rp, int* __restrict__ col,
    float* __restrict__ nin, float* __restrict__ nout,
    int n, int nbuck, int total) {
  __shared__ int cnt[BNODES];
  __shared__ int cur[BNODES];
  __shared__ int wsum[16];
  int tid = threadIdx.x;            // 0..1023
  if (blockIdx.x >= (unsigned)nbuck) {
    int b = blockIdx.x - nbuck;
    int base = bbaseS[b], end = bbaseS[b + 1];
    cnt[tid] = 0;
    if (b == 0 && tid == 0) nout[n] = 0.f;   // sentinel for pad gathers
    __syncthreads();
    for (int t = base + tid; t < end; t += 1024)
      atomicAdd(&cnt[(int)pairs2[t]], 1);
    __syncthreads();
    int node = (b << SHIFT) + tid;
    if (node < n) nout[node] = rsqrtf((float)(cnt[tid] + 1));   // +1 self-loop
    return;
  }
  int b = blockIdx.x;
  int base = bbase[b], end = bbase[b + 1];
  int node0 = b << SHIFT;
  cnt[tid] = 0;
  __syncthreads();
  for (int t = base + tid; t < end; t += 1024)
    atomicAdd(&cnt[(int)(pairs[t] >> 22)], 1);
  __syncthreads();
  int c = cnt[tid];
  // 2-level inclusive scan: wave shfl scan + 16 wave-sums
  int lane = tid & 63, wv = tid >> 6;
  int v = c;
  #pragma unroll
  for (int o = 1; o < 64; o <<= 1) {
    int t = __shfl_up(v, o, 64);
    if (lane >= o) v += t;
  }
  if (lane == 63) wsum[wv] = v;
  __syncthreads();
  if (tid < 16) {
    int w = wsum[tid];
    #pragma unroll
    for (int o = 1; o < 16; o <<= 1) {
      int t = __shfl_up(w, o, 64);
      if (lane >= o) w += t;
    }
    wsum[tid] = w;
  }
  __syncthreads();
  int incl = v + (wv ? wsum[wv - 1] : 0);
  int ex = incl - c;
  int node = node0 + tid;
  if (node < n) {
    rp[node] = base + ex;
    nin[node] = rsqrtf((float)c);              // in-degree incl self-loop
  }
  if (b == nbuck - 1 && tid == 0) rp[n] = total;
  cur[tid] = ex;
  __syncthreads();
  for (int t = base + tid; t < end; t += 1024) {
    u32 pr = pairs[t];
    int p = atomicAdd(&cur[(int)(pr >> 22)], 1);
    col[base + p] = (int)(pr & 0x3FFFFFu);
  }
}

// ---------- gather-aggregate (r8 engine) with fused per-src scale ----------
// mode 1: hsout[r] = bf16(nin[r]*sum_s snorm[s]*hs[s] + bias), XOR-swizzled
// mode 0: fout[r]  = fp32(nin[r]*sum_s hs[s] + bias), plain rows
__global__ __launch_bounds__(256) void k_agg(
    const u32* __restrict__ hs, const int* __restrict__ rp,
    const int* __restrict__ col, const float* __restrict__ nin,
    const float* __restrict__ snorm, const float* __restrict__ bias,
    float* __restrict__ fout, u32* __restrict__ hsout, int n, int mode) {
  int wid = (blockIdx.x * 256 + threadIdx.x) >> 6;   // global wave id
  int lane = threadIdx.x & 63;
  int g = lane >> 4, ch = lane & 15;
  int r = wid * 4 + g;
  bool valid = (r < n);
  int e0 = 0, e1 = 0;
  if (valid) { e0 = rp[r]; e1 = rp[r + 1]; }   // e1 > e0 (self-loop)
  int m = e1 - e0;
  m = max(m, __shfl_xor(m, 16, 64));
  m = max(m, __shfl_xor(m, 32, 64));
  int trips = (m + 7) >> 3;
  float acc[8] = {0.f, 0.f, 0.f, 0.f, 0.f, 0.f, 0.f, 0.f};
  const u32x4* hv = (const u32x4*)hs;   // 16 chunks per row
  int em1 = (e1 > 0) ? (e1 - 1) : 0;
  for (int it = 0; it < trips; ++it) {
    int tb = e0 + it * 8;
    u32x4 buf[8];
    float wb[8];
    #pragma unroll
    for (int u = 0; u < 8; ++u) {
      int idx = tb + u;
      int s = col[min(idx, em1)];          // group-uniform broadcast load
      s = (idx < e1) ? s : n;              // sentinel zero row for pads
      buf[u] = hv[(size_t)s * 16 + ch];
      if (mode) wb[u] = snorm[s];          // L2-resident 4B broadcast
    }
    #pragma unroll
    for (int u = 0; u < 8; ++u) {
      float w = mode ? wb[u] : 1.0f;
      #pragma unroll
      for (int j = 0; j < 4; ++j) {
        u32 x = buf[u][j];
        acc[2 * j]     = fmaf(__uint_as_float(x << 16), w, acc[2 * j]);
        acc[2 * j + 1] = fmaf(__uint_as_float(x & 0xFFFF0000u), w, acc[2 * j + 1]);
      }
    }
  }
  if (!valid) return;
  float wi = nin[r];
  float4 b0 = *(const float4*)(bias + ch * 8);
  float4 b1v = *(const float4*)(bias + ch * 8 + 4);
  float v[8];
  v[0] = acc[0] * wi + b0.x;  v[1] = acc[1] * wi + b0.y;
  v[2] = acc[2] * wi + b0.z;  v[3] = acc[3] * wi + b0.w;
  v[4] = acc[4] * wi + b1v.x; v[5] = acc[5] * wi + b1v.y;
  v[6] = acc[6] * wi + b1v.z; v[7] = acc[7] * wi + b1v.w;
  if (mode == 0) {
    *(float4*)(fout + (size_t)r * FD + ch * 8)     = make_float4(v[0], v[1], v[2], v[3]);
    *(float4*)(fout + (size_t)r * FD + ch * 8 + 4) = make_float4(v[4], v[5], v[6], v[7]);
  } else {
    u32 hi[4];
    #pragma unroll
    for (int j = 0; j < 4; ++j)
      hi[j] = (u32)f2bf(v[2 * j]) | ((u32)f2bf(v[2 * j + 1]) << 16);
    int sch = ch ^ (r & 7);               // 16B-chunk XOR swizzle
    u32x4 hq = {hi[0], hi[1], hi[2], hi[3]};
    *(u32x4*)(hsout + (size_t)r * 64 + sch * 4) = hq;
  }
}

// ---------- Y2 = bf16(nout * (h1 @ W2)): MFMA GEMM, LDS-staged coalesced epi ----------
__global__ __launch_bounds__(256) void k_gemm2(
    const u32* __restrict__ ahi,
    const u32* __restrict__ wfhi, const u32* __restrict__ wflo,
    const float* __restrict__ nout, u32* __restrict__ yout, int n) {
  __shared__ u32 As[4096];   // 16 KB: swizzled input stage, then epi staging
  int tid = threadIdx.x;
  int lane = tid & 63;
  int mt = tid >> 6;
  int r0 = blockIdx.x * 64;

  const u32x4* gh = (const u32x4*)(ahi + (size_t)r0 * 64);
  u32x4* sh_ = (u32x4*)As;
  #pragma unroll
  for (int t = 0; t < 4; ++t) sh_[t * 256 + tid] = gh[t * 256 + tid];
  __syncthreads();

  short8 afh[4];
  int arow = mt * 16 + (lane & 15);
  #pragma unroll
  for (int kt = 0; kt < 4; ++kt) {
    int boff = arow * 256 + ((kt * 64 + (lane >> 4) * 16) ^ ((arow & 7) << 4));
    afh[kt] = *(const short8*)((const char*)As + boff);
  }
  __syncthreads();   // As dead -> reuse for epilogue

  float wout[4];
  #pragma unroll
  for (int j = 0; j < 4; ++j) {
    int row = r0 + mt * 16 + (lane >> 4) * 4 + j;
    wout[j] = (row < n) ? nout[row] : 0.f;
  }

  for (int nt = 0; nt < 8; ++nt) {
    f32x4 oacc = {0.f, 0.f, 0.f, 0.f};
    #pragma unroll
    for (int kt = 0; kt < 4; ++kt) {
      int f = nt * 4 + kt;
      short8 wh = *(const short8*)(wfhi + (size_t)(f * 64 + lane) * 4);
      short8 wl = *(const short8*)(wflo + (size_t)(f * 64 + lane) * 4);
      oacc = __builtin_amdgcn_mfma_f32_16x16x32_bf16(afh[kt], wh, oacc, 0, 0, 0);
      oacc = __builtin_amdgcn_mfma_f32_16x16x32_bf16(afh[kt], wl, oacc, 0, 0, 0);
    }
    int c = nt * 16 + (lane & 15);
    #pragma unroll
    for (int j = 0; j < 4; ++j) {
      int lrow = mt * 16 + (lane >> 4) * 4 + j;
      ((u16*)As)[lrow * 128 + c] = f2bf(oacc[j] * wout[j]);   // no bias here
    }
  }
  __syncthreads();
  #pragma unroll
  for (int it = 0; it < 4; ++it) {
    int ci = it * 256 + tid;
    int lrow = ci >> 4, chk = ci & 15;
    int row = r0 + lrow;
    if (row < n)
      *(u32x4*)(yout + (size_t)row * 64 + chk * 4) =
          *(const u32x4*)(As + lrow * 64 + chk * 4);
  }
}

// ---------------- launch ----------------
extern "C" void kernel_launch(void* const* d_in, const int* in_sizes, int n_in,
                              void* d_out, int out_size, void* d_ws, size_t ws_size,
                              hipStream_t stream) {
  const float* x  = (const float*)d_in[0];
  const int* src  = (const int*)d_in[1];
  const int* dst  = (const int*)d_in[2];
  const float* W1 = (const float*)d_in[3];
  const float* b1 = (const float*)d_in[4];
  const float* W2 = (const float*)d_in[5];
  const float* b2 = (const float*)d_in[6];
  float* out = (float*)d_out;

  int n = in_sizes[0] / FD;      // 100000
  int e = in_sizes[1];           // 1600000
  int total = e + n;
  int nbuck = (n + BNODES - 1) >> SHIFT;   // 98

  char* ws = (char*)d_ws;
  size_t off = 0;
  auto alloc = [&](size_t bytes) -> void* {
    void* p = ws + off;
    off += (bytes + 255) / 256 * 256;
    return p;
  };
  // bufA: T1bf then Y2 (T1 dead after agg1; row n stays 0 from the memset)
  u32* bufA  = (u32*)alloc((size_t)(n + 16) * 64 * 4);   // 25.6 MB
  u32* t1bf  = bufA;
  u32* y2    = bufA;
  u32* pairs = (u32*)alloc((size_t)total * 4 + 256);     // 6.8 MB
  // bufC: pairs2 (build phase) then h1bf (+64-row pad for gemm2 staging reads)
  u32* bufC  = (u32*)alloc((size_t)(n + 64) * 64 * 4);   // 25.6 MB
  u16* pairs2 = (u16*)bufC;
  u32* h1bf  = bufC;
  int* col   = (int*)alloc((size_t)total * 4 + 256);     // 6.8 MB
  int* rp    = (int*)alloc((size_t)(n + 1) * 4);
  float* nin  = (float*)alloc((size_t)n * 4);
  float* nout = (float*)alloc((size_t)(n + 16) * 4);     // +sentinel slot n
  int* bcntD  = (int*)alloc(NBK * 4);
  int* bcntS  = (int*)alloc(NBK * 4);
  int* bbaseD = (int*)alloc((NBK + 1) * 4);
  int* bbaseS = (int*)alloc((NBK + 1) * 4);
  int* bcurD  = (int*)alloc(NBK * 4);
  int* bcurS  = (int*)alloc(NBK * 4);
  u32* wf1hi  = (u32*)alloc(8192 * 4);
  u32* wf1lo  = (u32*)alloc(8192 * 4);
  u32* wf2hi  = (u32*)alloc(8192 * 4);
  u32* wf2lo  = (u32*)alloc(8192 * 4);

  hipMemsetAsync(bcntD, 0, (size_t)NBK * 4 * 2, stream);     // bcntD+bcntS contiguous
  hipMemsetAsync(bufA + (size_t)n * 64, 0, 64 * 4, stream);  // T1/Y2 sentinel row n

  // hist + W-prep (independent work, one launch)
  k_histpw<<<288, 512, 0, stream>>>(src, dst, bcntD, bcntS, e, n, nbuck,
                                    W1, wf1hi, wf1lo, W2, wf2hi, wf2lo);
  k_bscan<<<1, NBK, 0, stream>>>(bcntD, bcntS, bbaseD, bcurD, bbaseS, bcurS,
                                 nbuck, total, e);
  // scatter ∥ T1 = bf16(X @ W1)
  int nsc = (total + CHUNK - 1) / CHUNK;           // 208
  int ngx = (n + 127) / 128;                       // 782 (two 64-row units each)
  k_scatgx<<<nsc + ngx, ST, 0, stream>>>(src, dst, bcurD, bcurS, pairs, pairs2,
                                         e, n, nbuck, nsc, x, wf1hi, wf1lo, t1bf);
  k_build<<<2 * nbuck, 1024, 0, stream>>>(pairs, bbaseD, pairs2, bbaseS,
                                          rp, col, nin, nout, n, nbuck, total);

  int agrid = (n + 15) / 16;     // 4 rows/wave, 4 waves/block
  int ggrid = (n + 63) / 64;
  // h1 = bf16(nin * sum_s nout[s]*T1[s] + b1), swizzled for gemm2
  k_agg<<<agrid, 256, 0, stream>>>(t1bf, rp, col, nin, nout, b1,
                                   nullptr, h1bf, n, 1);
  // Y2 = bf16(nout * (h1 @ W2))
  k_gemm2<<<ggrid, 256, 0, stream>>>(h1bf, wf2hi, wf2lo, nout, y2, n);
  // out = nin * gather(Y2) + b2   (fp32)
  k_agg<<<agrid, 256, 0, stream>>>(y2, rp, col, nin, nullptr, b2,
                                   out, nullptr, n, 0);
}

// Round 16
// 222.661 us; speedup vs baseline: 1.1628x; 1.1628x over previous
//
#include <hip/hip_runtime.h>

#define FD 128
#define SHIFT 10         // nodes per bucket = 1024
#define BNODES 1024
#define NBK 128          // padded bucket-array size (98 used)
#define CHUNK 8192       // edges per scatter block
#define ST 512           // scatter block threads
#define NIT 16           // items per thread in scatter

typedef unsigned int u32;
typedef unsigned short u16;
typedef unsigned char u8;
typedef __attribute__((ext_vector_type(8))) short short8;   // 8 bf16 (4 VGPR)
typedef __attribute__((ext_vector_type(4))) float f32x4;
typedef __attribute__((ext_vector_type(4))) u32 u32x4;

__device__ inline u16 f2bf(float f) {            // fp32 -> bf16 RNE
  u32 u = __float_as_uint(f);
  u += 0x7fffu + ((u >> 16) & 1u);
  return (u16)(u >> 16);
}
__device__ inline float bf2f(u16 h) { return __uint_as_float((u32)h << 16); }

// ---------- pass 0: bucket histograms + W-prep in one launch ----------
__global__ __launch_bounds__(512) void k_histpw(
    const int* __restrict__ src, const int* __restrict__ dst,
    int* __restrict__ bcntD, int* __restrict__ bcntS, int e, int n, int nbuck,
    const float* __restrict__ W1, u32* __restrict__ wf1hi, u32* __restrict__ wf1lo,
    const float* __restrict__ W2, u32* __restrict__ wf2hi, u32* __restrict__ wf2lo) {
  int tid = threadIdx.x;
  if (blockIdx.x >= 256) {
    int gi = (blockIdx.x - 256) * 512 + tid;   // 0..16383
    int i = gi & 8191;
    const float* W = (gi < 8192) ? W1 : W2;
    u32* wfhi = (gi < 8192) ? wf1hi : wf2hi;
    u32* wflo = (gi < 8192) ? wf1lo : wf2lo;
    int m = i & 3, l = (i >> 2) & 63, f = i >> 8;
    int kt = f & 3, nt = f >> 2;
    int k0 = kt * 32 + ((l >> 4) << 3) + 2 * m;
    int c = nt * 16 + (l & 15);
    float w0 = W[k0 * FD + c], w1 = W[(k0 + 1) * FD + c];
    u16 h0 = f2bf(w0), h1 = f2bf(w1);
    u16 l0 = f2bf(w0 - bf2f(h0)), l1 = f2bf(w1 - bf2f(h1));
    wfhi[i] = (u32)h0 | ((u32)h1 << 16);
    wflo[i] = (u32)l0 | ((u32)l1 << 16);
    return;
  }
  __shared__ int shD[NBK];
  __shared__ int shS[NBK];
  if (tid < NBK) { shD[tid] = 0; shS[tid] = 0; }
  __syncthreads();
  int total = e + n;
  for (int t = blockIdx.x * 512 + tid; t < total; t += 256 * 512) {
    if (t < e) {
      atomicAdd(&shD[dst[t] >> SHIFT], 1);
      atomicAdd(&shS[src[t] >> SHIFT], 1);
    } else {
      atomicAdd(&shD[(t - e) >> SHIFT], 1);
    }
  }
  __syncthreads();
  if (tid < nbuck) {
    if (shD[tid]) atomicAdd(&bcntD[tid], shD[tid]);
    if (shS[tid]) atomicAdd(&bcntS[tid], shS[tid]);
  }
}

// ---------- pass 1: scan both bucket arrays ----------
__global__ __launch_bounds__(NBK) void k_bscan(
    const int* __restrict__ bcntD, const int* __restrict__ bcntS,
    int* __restrict__ bbaseD, int* __restrict__ bcurD,
    int* __restrict__ bbaseS, int* __restrict__ bcurS,
    int nbuck, int totalD, int totalS) {
  __shared__ int shD[NBK];
  __shared__ int shS[NBK];
  int tid = threadIdx.x;
  int vD = (tid < nbuck) ? bcntD[tid] : 0;
  int vS = (tid < nbuck) ? bcntS[tid] : 0;
  shD[tid] = vD; shS[tid] = vS;
  __syncthreads();
  for (int off = 1; off < NBK; off <<= 1) {
    int aD = (tid >= off) ? shD[tid - off] : 0;
    int aS = (tid >= off) ? shS[tid - off] : 0;
    __syncthreads();
    shD[tid] += aD; shS[tid] += aS;
    __syncthreads();
  }
  if (tid < nbuck) {
    int exD = shD[tid] - vD; bbaseD[tid] = exD; bcurD[tid] = exD;
    int exS = shS[tid] - vS; bbaseS[tid] = exS; bcurS[tid] = exS;
  }
  if (tid == 0) { bbaseD[nbuck] = totalD; bbaseS[nbuck] = totalS; }
}

// ---------- pass 2: scatter (blocks [0,nsc)) ∥ T1 = bf16(X@W1) (blocks [nsc,..)) ----------
__global__ __launch_bounds__(ST) void k_scatgx(
    const int* __restrict__ src, const int* __restrict__ dst,
    int* __restrict__ bcurD, int* __restrict__ bcurS,
    u32* __restrict__ pairs, u16* __restrict__ pairs2,
    int e, int n, int nbuck, int nsc,
    const float* __restrict__ x,
    const u32* __restrict__ wfhi, const u32* __restrict__ wflo,
    u32* __restrict__ tout) {
  __shared__ __align__(16) u8 smem[45056];   // 44 KB arena
  int tid512 = threadIdx.x;

  if (blockIdx.x >= (unsigned)nsc) {
    // ---- gemmx: two independent 64-row units (u = tid>>8) ----
    int u = tid512 >> 8, tid = tid512 & 255;
    u32* Au = (u32*)smem + u * 4096;   // 16 KB per unit
    int lane = tid & 63;
    int mt = tid >> 6;
    int r0 = ((blockIdx.x - nsc) * 2 + u) * 64;

    #pragma unroll
    for (int it = 0; it < 16; ++it) {
      int w = it * 256 + tid;
      int row = w >> 6, uu = w & 63;
      int grow = r0 + row;
      float2 v = make_float2(0.f, 0.f);
      if (grow < n) v = *(const float2*)(x + (size_t)grow * FD + uu * 2);
      Au[row * 64 + (uu ^ ((row & 7) << 2))] = (u32)f2bf(v.x) | ((u32)f2bf(v.y) << 16);
    }
    __syncthreads();

    short8 afh[4];
    int arow = mt * 16 + (lane & 15);
    #pragma unroll
    for (int kt = 0; kt < 4; ++kt) {
      int boff = arow * 256 + ((kt * 64 + (lane >> 4) * 16) ^ ((arow & 7) << 4));
      afh[kt] = *(const short8*)((const char*)Au + boff);
    }
    __syncthreads();   // Au dead -> epilogue staging

    for (int nt = 0; nt < 8; ++nt) {
      f32x4 oacc = {0.f, 0.f, 0.f, 0.f};
      #pragma unroll
      for (int kt = 0; kt < 4; ++kt) {
        int f = nt * 4 + kt;
        short8 wh = *(const short8*)(wfhi + (size_t)(f * 64 + lane) * 4);
        short8 wl = *(const short8*)(wflo + (size_t)(f * 64 + lane) * 4);
        oacc = __builtin_amdgcn_mfma_f32_16x16x32_bf16(afh[kt], wh, oacc, 0, 0, 0);
        oacc = __builtin_amdgcn_mfma_f32_16x16x32_bf16(afh[kt], wl, oacc, 0, 0, 0);
      }
      int c = nt * 16 + (lane & 15);
      #pragma unroll
      for (int j = 0; j < 4; ++j) {
        int lrow = mt * 16 + (lane >> 4) * 4 + j;
        ((u16*)Au)[lrow * 128 + c] = f2bf(oacc[j]);   // no bias, no scale
      }
    }
    __syncthreads();
    #pragma unroll
    for (int it = 0; it < 4; ++it) {
      int ci = it * 256 + tid;
      int lrow = ci >> 4, chk = ci & 15;
      int row = r0 + lrow;
      if (row < n)
        *(u32x4*)(tout + (size_t)row * 64 + chk * 4) =
            *(const u32x4*)(Au + lrow * 64 + chk * 4);
    }
    return;
  }

  // ---- scatter ----
  int* histD = (int*)smem;               // 8 x 128 ints = 4 KB
  int* exclD = histD + NBK;
  int* gbaseD = exclD + NBK;
  int* rankD = gbaseD + NBK;
  int* histS = rankD + NBK;
  int* exclS = histS + NBK;
  int* gbaseS = exclS + NBK;
  int* rankS = gbaseS + NBK;
  u32* stgv = (u32*)(smem + 4096);       // 32 KB (phase A)
  u8*  stgb = smem + 36864;              // 8 KB  (phase A)
  u16* stg2 = (u16*)(smem + 4096);       // 16 KB (phase B, reuses stgv)
  u8*  stg2b = smem + 20480;             // 8 KB  (phase B)
  int tid = tid512;
  int c0 = blockIdx.x * CHUNK;
  int total = e + n;
  if (tid < NBK) { histD[tid] = 0; histS[tid] = 0; }
  __syncthreads();
  u32 pv_[NIT]; int bD_[NIT], bS_[NIT]; bool v_[NIT], vs_[NIT];
  #pragma unroll
  for (int i = 0; i < NIT; ++i) {
    int t = c0 + i * ST + tid;
    v_[i] = (t < total);
    vs_[i] = (t < e);
    pv_[i] = 0; bD_[i] = 0; bS_[i] = 0;
    if (v_[i]) {
      int s, d;
      if (vs_[i]) { s = src[t]; d = dst[t]; }
      else        { s = t - e;  d = s; }
      pv_[i] = ((u32)(d & (BNODES - 1)) << 22) | (u32)s;
      bD_[i] = d >> SHIFT;
      atomicAdd(&histD[bD_[i]], 1);
      if (vs_[i]) { bS_[i] = s >> SHIFT; atomicAdd(&histS[bS_[i]], 1); }
    }
  }
  __syncthreads();
  int hD = 0, hS = 0;
  if (tid < NBK) { hD = histD[tid]; hS = histS[tid]; }
  __syncthreads();
  for (int off = 1; off < NBK; off <<= 1) {
    int aD = 0, aS = 0;
    if (tid < NBK && tid >= off) { aD = histD[tid - off]; aS = histS[tid - off]; }
    __syncthreads();
    if (tid < NBK) { histD[tid] += aD; histS[tid] += aS; }
    __syncthreads();
  }
  if (tid < NBK) {
    int exD = histD[tid] - hD; exclD[tid] = exD; rankD[tid] = exD;
    int exS = histS[tid] - hS; exclS[tid] = exS; rankS[tid] = exS;
    gbaseD[tid] = (tid < nbuck && hD > 0) ? atomicAdd(&bcurD[tid], hD) : 0;
    gbaseS[tid] = (tid < nbuck && hS > 0) ? atomicAdd(&bcurS[tid], hS) : 0;
  }
  __syncthreads();
  // phase A: dst-keyed pairs
  #pragma unroll
  for (int i = 0; i < NIT; ++i) {
    if (v_[i]) {
      int p = atomicAdd(&rankD[bD_[i]], 1);
      stgv[p] = pv_[i];
      stgb[p] = (u8)bD_[i];
    }
  }
  __syncthreads();
  int V = min(CHUNK, total - c0);
  for (int j = tid; j < V; j += ST) {
    int b = stgb[j];
    pairs[gbaseD[b] + (j - exclD[b])] = stgv[j];   // contiguous runs per bucket
  }
  __syncthreads();   // LDS reuse fence
  // phase B: src-keyed pairs2
  #pragma unroll
  for (int i = 0; i < NIT; ++i) {
    if (vs_[i]) {
      int p = atomicAdd(&rankS[bS_[i]], 1);
      stg2[p] = (u16)(pv_[i] & (BNODES - 1));   // local src id
      stg2b[p] = (u8)bS_[i];
    }
  }
  __syncthreads();
  int V2 = min(CHUNK, e - c0);                     // negative -> loop skipped
  for (int j = tid; j < V2; j += ST) {
    int b = stg2b[j];
    pairs2[gbaseS[b] + (j - exclS[b])] = stg2[j];
  }
}

// ---------- pass 3: merged per-bucket finalize (fast 2-level scan) ----------
__global__ __launch_bounds__(1024) void k_build(
    const u32* __restrict__ pairs, const int* __restrict__ bbase,
    const u16* __restrict__ pairs2, const int* __restrict__ bbaseS,
    int* __restrict__ rp, int* __restrict__ col,
    float* __restrict__ nin, float* __restrict__ nout,
    int n, int nbuck, int total) {
  __shared__ int cnt[BNODES];
  __shared__ int cur[BNODES];
  __shared__ int wsum[16];
  int tid = threadIdx.x;            // 0..1023
  if (blockIdx.x >= (unsigned)nbuck) {
    int b = blockIdx.x - nbuck;
    int base = bbaseS[b], end = bbaseS[b + 1];
    cnt[tid] = 0;
    if (b == 0 && tid == 0) nout[n] = 0.f;   // sentinel for pad gathers
    __syncthreads();
    for (int t = base + tid; t < end; t += 1024)
      atomicAdd(&cnt[(int)pairs2[t]], 1);
    __syncthreads();
    int node = (b << SHIFT) + tid;
    if (node < n) nout[node] = rsqrtf((float)(cnt[tid] + 1));   // +1 self-loop
    return;
  }
  int b = blockIdx.x;
  int base = bbase[b], end = bbase[b + 1];
  int node0 = b << SHIFT;
  cnt[tid] = 0;
  __syncthreads();
  for (int t = base + tid; t < end; t += 1024)
    atomicAdd(&cnt[(int)(pairs[t] >> 22)], 1);
  __syncthreads();
  int c = cnt[tid];
  // 2-level inclusive scan: wave shfl scan + 16 wave-sums
  int lane = tid & 63, wv = tid >> 6;
  int v = c;
  #pragma unroll
  for (int o = 1; o < 64; o <<= 1) {
    int t = __shfl_up(v, o, 64);
    if (lane >= o) v += t;
  }
  if (lane == 63) wsum[wv] = v;
  __syncthreads();
  if (tid < 16) {
    int w = wsum[tid];
    #pragma unroll
    for (int o = 1; o < 16; o <<= 1) {
      int t = __shfl_up(w, o, 64);
      if (lane >= o) w += t;
    }
    wsum[tid] = w;
  }
  __syncthreads();
  int incl = v + (wv ? wsum[wv - 1] : 0);
  int ex = incl - c;
  int node = node0 + tid;
  if (node < n) {
    rp[node] = base + ex;
    nin[node] = rsqrtf((float)c);              // in-degree incl self-loop
  }
  if (b == nbuck - 1 && tid == 0) rp[n] = total;
  cur[tid] = ex;
  __syncthreads();
  for (int t = base + tid; t < end; t += 1024) {
    u32 pr = pairs[t];
    int p = atomicAdd(&cur[(int)(pr >> 22)], 1);
    col[base + p] = (int)(pr & 0x3FFFFFu);
  }
}

// ---------- gather-aggregate: MODE is compile-time, two clean codegens ----------
// MODE 1: hsout[r] = bf16(nin[r]*sum_s snorm[s]*hs[s] + bias), XOR-swizzled
// MODE 0: fout[r]  = fp32(nin[r]*sum_s hs[s] + bias), plain rows
template <int MODE>
__global__ __launch_bounds__(256) void k_agg(
    const u32* __restrict__ hs, const int* __restrict__ rp,
    const int* __restrict__ col, const float* __restrict__ nin,
    const float* __restrict__ snorm, const float* __restrict__ bias,
    float* __restrict__ fout, u32* __restrict__ hsout, int n) {
  int wid = (blockIdx.x * 256 + threadIdx.x) >> 6;   // global wave id
  int lane = threadIdx.x & 63;
  int g = lane >> 4, ch = lane & 15;
  int r = wid * 4 + g;
  bool valid = (r < n);
  int e0 = 0, e1 = 0;
  if (valid) { e0 = rp[r]; e1 = rp[r + 1]; }   // e1 > e0 (self-loop)
  int m = e1 - e0;
  m = max(m, __shfl_xor(m, 16, 64));
  m = max(m, __shfl_xor(m, 32, 64));
  int trips = (m + 7) >> 3;
  float acc[8] = {0.f, 0.f, 0.f, 0.f, 0.f, 0.f, 0.f, 0.f};
  const u32x4* hv = (const u32x4*)hs;   // 16 chunks per row
  int em1 = (e1 > 0) ? (e1 - 1) : 0;
  for (int it = 0; it < trips; ++it) {
    int tb = e0 + it * 8;
    u32x4 buf[8];
    float wb[8];
    #pragma unroll
    for (int u = 0; u < 8; ++u) {
      int idx = tb + u;
      int s = col[min(idx, em1)];          // group-uniform broadcast load
      s = (idx < e1) ? s : n;              // sentinel zero row for pads
      buf[u] = hv[(size_t)s * 16 + ch];
      if (MODE) wb[u] = snorm[s];          // L2-resident 4B broadcast
    }
    if (MODE) {
      #pragma unroll
      for (int u = 0; u < 8; ++u)
        #pragma unroll
        for (int j = 0; j < 4; ++j) {
          u32 x = buf[u][j];
          acc[2 * j]     = fmaf(__uint_as_float(x << 16), wb[u], acc[2 * j]);
          acc[2 * j + 1] = fmaf(__uint_as_float(x & 0xFFFF0000u), wb[u], acc[2 * j + 1]);
        }
    } else {
      #pragma unroll
      for (int u = 0; u < 8; ++u)
        #pragma unroll
        for (int j = 0; j < 4; ++j) {
          u32 x = buf[u][j];
          acc[2 * j]     += __uint_as_float(x << 16);
          acc[2 * j + 1] += __uint_as_float(x & 0xFFFF0000u);
        }
    }
  }
  if (!valid) return;
  float wi = nin[r];
  float4 b0 = *(const float4*)(bias + ch * 8);
  float4 b1v = *(const float4*)(bias + ch * 8 + 4);
  float v[8];
  v[0] = acc[0] * wi + b0.x;  v[1] = acc[1] * wi + b0.y;
  v[2] = acc[2] * wi + b0.z;  v[3] = acc[3] * wi + b0.w;
  v[4] = acc[4] * wi + b1v.x; v[5] = acc[5] * wi + b1v.y;
  v[6] = acc[6] * wi + b1v.z; v[7] = acc[7] * wi + b1v.w;
  if (MODE == 0) {
    *(float4*)(fout + (size_t)r * FD + ch * 8)     = make_float4(v[0], v[1], v[2], v[3]);
    *(float4*)(fout + (size_t)r * FD + ch * 8 + 4) = make_float4(v[4], v[5], v[6], v[7]);
  } else {
    u32 hi[4];
    #pragma unroll
    for (int j = 0; j < 4; ++j)
      hi[j] = (u32)f2bf(v[2 * j]) | ((u32)f2bf(v[2 * j + 1]) << 16);
    int sch = ch ^ (r & 7);               // 16B-chunk XOR swizzle
    u32x4 hq = {hi[0], hi[1], hi[2], hi[3]};
    *(u32x4*)(hsout + (size_t)r * 64 + sch * 4) = hq;
  }
}

// ---------- Y2 = bf16(nout * (h1 @ W2)): MFMA GEMM, LDS-staged coalesced epi ----------
__global__ __launch_bounds__(256) void k_gemm2(
    const u32* __restrict__ ahi,
    const u32* __restrict__ wfhi, const u32* __restrict__ wflo,
    const float* __restrict__ nout, u32* __restrict__ yout, int n) {
  __shared__ u32 As[4096];   // 16 KB: swizzled input stage, then epi staging
  int tid = threadIdx.x;
  int lane = tid & 63;
  int mt = tid >> 6;
  int r0 = blockIdx.x * 64;

  const u32x4* gh = (const u32x4*)(ahi + (size_t)r0 * 64);
  u32x4* sh_ = (u32x4*)As;
  #pragma unroll
  for (int t = 0; t < 4; ++t) sh_[t * 256 + tid] = gh[t * 256 + tid];
  __syncthreads();

  short8 afh[4];
  int arow = mt * 16 + (lane & 15);
  #pragma unroll
  for (int kt = 0; kt < 4; ++kt) {
    int boff = arow * 256 + ((kt * 64 + (lane >> 4) * 16) ^ ((arow & 7) << 4));
    afh[kt] = *(const short8*)((const char*)As + boff);
  }
  __syncthreads();   // As dead -> reuse for epilogue

  float wout[4];
  #pragma unroll
  for (int j = 0; j < 4; ++j) {
    int row = r0 + mt * 16 + (lane >> 4) * 4 + j;
    wout[j] = (row < n) ? nout[row] : 0.f;
  }

  for (int nt = 0; nt < 8; ++nt) {
    f32x4 oacc = {0.f, 0.f, 0.f, 0.f};
    #pragma unroll
    for (int kt = 0; kt < 4; ++kt) {
      int f = nt * 4 + kt;
      short8 wh = *(const short8*)(wfhi + (size_t)(f * 64 + lane) * 4);
      short8 wl = *(const short8*)(wflo + (size_t)(f * 64 + lane) * 4);
      oacc = __builtin_amdgcn_mfma_f32_16x16x32_bf16(afh[kt], wh, oacc, 0, 0, 0);
      oacc = __builtin_amdgcn_mfma_f32_16x16x32_bf16(afh[kt], wl, oacc, 0, 0, 0);
    }
    int c = nt * 16 + (lane & 15);
    #pragma unroll
    for (int j = 0; j < 4; ++j) {
      int lrow = mt * 16 + (lane >> 4) * 4 + j;
      ((u16*)As)[lrow * 128 + c] = f2bf(oacc[j] * wout[j]);   // no bias here
    }
  }
  __syncthreads();
  #pragma unroll
  for (int it = 0; it < 4; ++it) {
    int ci = it * 256 + tid;
    int lrow = ci >> 4, chk = ci & 15;
    int row = r0 + lrow;
    if (row < n)
      *(u32x4*)(yout + (size_t)row * 64 + chk * 4) =
          *(const u32x4*)(As + lrow * 64 + chk * 4);
  }
}

// ---------------- launch ----------------
extern "C" void kernel_launch(void* const* d_in, const int* in_sizes, int n_in,
                              void* d_out, int out_size, void* d_ws, size_t ws_size,
                              hipStream_t stream) {
  const float* x  = (const float*)d_in[0];
  const int* src  = (const int*)d_in[1];
  const int* dst  = (const int*)d_in[2];
  const float* W1 = (const float*)d_in[3];
  const float* b1 = (const float*)d_in[4];
  const float* W2 = (const float*)d_in[5];
  const float* b2 = (const float*)d_in[6];
  float* out = (float*)d_out;

  int n = in_sizes[0] / FD;      // 100000
  int e = in_sizes[1];           // 1600000
  int total = e + n;
  int nbuck = (n + BNODES - 1) >> SHIFT;   // 98

  char* ws = (char*)d_ws;
  size_t off = 0;
  auto alloc = [&](size_t bytes) -> void* {
    void* p = ws + off;
    off += (bytes + 255) / 256 * 256;
    return p;
  };
  // bufA: T1bf then Y2 (T1 dead after agg1; row n stays 0 from the memset)
  u32* bufA  = (u32*)alloc((size_t)(n + 16) * 64 * 4);   // 25.6 MB
  u32* t1bf  = bufA;
  u32* y2    = bufA;
  u32* pairs = (u32*)alloc((size_t)total * 4 + 256);     // 6.8 MB
  // bufC: pairs2 (build phase) then h1bf (+64-row pad for gemm2 staging reads)
  u32* bufC  = (u32*)alloc((size_t)(n + 64) * 64 * 4);   // 25.6 MB
  u16* pairs2 = (u16*)bufC;
  u32* h1bf  = bufC;
  int* col   = (int*)alloc((size_t)total * 4 + 256);     // 6.8 MB
  int* rp    = (int*)alloc((size_t)(n + 1) * 4);
  float* nin  = (float*)alloc((size_t)n * 4);
  float* nout = (float*)alloc((size_t)(n + 16) * 4);     // +sentinel slot n
  int* bcntD  = (int*)alloc(NBK * 4);
  int* bcntS  = (int*)alloc(NBK * 4);
  int* bbaseD = (int*)alloc((NBK + 1) * 4);
  int* bbaseS = (int*)alloc((NBK + 1) * 4);
  int* bcurD  = (int*)alloc(NBK * 4);
  int* bcurS  = (int*)alloc(NBK * 4);
  u32* wf1hi  = (u32*)alloc(8192 * 4);
  u32* wf1lo  = (u32*)alloc(8192 * 4);
  u32* wf2hi  = (u32*)alloc(8192 * 4);
  u32* wf2lo  = (u32*)alloc(8192 * 4);

  hipMemsetAsync(bcntD, 0, (size_t)NBK * 4 * 2, stream);     // bcntD+bcntS contiguous
  hipMemsetAsync(bufA + (size_t)n * 64, 0, 64 * 4, stream);  // T1/Y2 sentinel row n

  // hist + W-prep (independent work, one launch)
  k_histpw<<<288, 512, 0, stream>>>(src, dst, bcntD, bcntS, e, n, nbuck,
                                    W1, wf1hi, wf1lo, W2, wf2hi, wf2lo);
  k_bscan<<<1, NBK, 0, stream>>>(bcntD, bcntS, bbaseD, bcurD, bbaseS, bcurS,
                                 nbuck, total, e);
  // scatter ∥ T1 = bf16(X @ W1)
  int nsc = (total + CHUNK - 1) / CHUNK;           // 208
  int ngx = (n + 127) / 128;                       // 782 (two 64-row units each)
  k_scatgx<<<nsc + ngx, ST, 0, stream>>>(src, dst, bcurD, bcurS, pairs, pairs2,
                                         e, n, nbuck, nsc, x, wf1hi, wf1lo, t1bf);
  k_build<<<2 * nbuck, 1024, 0, stream>>>(pairs, bbaseD, pairs2, bbaseS,
                                          rp, col, nin, nout, n, nbuck, total);

  int agrid = (n + 15) / 16;     // 4 rows/wave, 4 waves/block
  int ggrid = (n + 63) / 64;
  // h1 = bf16(nin * sum_s nout[s]*T1[s] + b1), swizzled for gemm2
  k_agg<1><<<agrid, 256, 0, stream>>>(t1bf, rp, col, nin, nout, b1,
                                      nullptr, h1bf, n);
  // Y2 = bf16(nout * (h1 @ W2))
  k_gemm2<<<ggrid, 256, 0, stream>>>(h1bf, wf2hi, wf2lo, nout, y2, n);
  // out = nin * gather(Y2) + b2   (fp32)
  k_agg<0><<<agrid, 256, 0, stream>>>(y2, rp, col, nin, nullptr, b2,
                                      out, nullptr, n);
}

// Round 18
// 217.536 us; speedup vs baseline: 1.1902x; 1.0236x over previous
//
#include <hip/hip_runtime.h>

#define FD 128
#define SHIFT 10         // nodes per bucket = 1024
#define BNODES 1024
#define NBK 128          // padded bucket-array size (98 used)
#define CHUNK 8192       // edges per scatter block
#define ST 512           // scatter block threads
#define NIT 16           // items per thread in scatter

typedef unsigned int u32;
typedef unsigned short u16;
typedef unsigned char u8;
typedef __attribute__((ext_vector_type(8))) short short8;   // 8 bf16 (4 VGPR)
typedef __attribute__((ext_vector_type(4))) float f32x4;
typedef __attribute__((ext_vector_type(4))) u32 u32x4;

__device__ inline u16 f2bf(float f) {            // fp32 -> bf16 RNE
  u32 u = __float_as_uint(f);
  u += 0x7fffu + ((u >> 16) & 1u);
  return (u16)(u >> 16);
}
__device__ inline float bf2f(u16 h) { return __uint_as_float((u32)h << 16); }

// ---------- pass 0: W1/W2 -> fragment-ordered split-bf16 planes ----------
// MUST be its own launch: k_scatgx's gemmx blocks consume these planes, and
// blocks within one launch have no ordering guarantee (r17 race).
__global__ __launch_bounds__(512) void k_prepw(
    const float* __restrict__ W1, u32* __restrict__ wf1hi, u32* __restrict__ wf1lo,
    const float* __restrict__ W2, u32* __restrict__ wf2hi, u32* __restrict__ wf2lo) {
  int gi = blockIdx.x * 512 + threadIdx.x;   // 0..16383
  int i = gi & 8191;
  const float* W = (gi < 8192) ? W1 : W2;
  u32* whi = (gi < 8192) ? wf1hi : wf2hi;
  u32* wlo = (gi < 8192) ? wf1lo : wf2lo;
  int m = i & 3, l = (i >> 2) & 63, f = i >> 8;
  int kt = f & 3, nt = f >> 2;
  int k0 = kt * 32 + ((l >> 4) << 3) + 2 * m;
  int c = nt * 16 + (l & 15);
  float w0 = W[k0 * FD + c], w1 = W[(k0 + 1) * FD + c];
  u16 h0 = f2bf(w0), h1 = f2bf(w1);
  u16 l0 = f2bf(w0 - bf2f(h0)), l1 = f2bf(w1 - bf2f(h1));
  whi[i] = (u32)h0 | ((u32)h1 << 16);
  wlo[i] = (u32)l0 | ((u32)l1 << 16);
}

// ---------- pass 1: scatter (blocks [0,nsc)) ∥ T1=bf16(X@W1) (blocks [nsc,..)) ----------
// Scatter chunk i -> pairs[i*CHUNK..] (bucket-sorted within block, linear
// coalesced dump) + per-block bucket offset tables ofsD/ofsS[b*nsc+i].
__global__ __launch_bounds__(ST) void k_scatgx(
    const int* __restrict__ src, const int* __restrict__ dst,
    u32* __restrict__ pairs, u16* __restrict__ pairs2,
    int* __restrict__ ofsD, int* __restrict__ ofsS,
    int e, int n, int nbuck, int nsc,
    const float* __restrict__ x,
    const u32* __restrict__ wfhi, const u32* __restrict__ wflo,
    u32* __restrict__ tout) {
  __shared__ __align__(16) u8 smem[36864];   // 36 KB arena
  int tid512 = threadIdx.x;

  if (blockIdx.x >= (unsigned)nsc) {
    // ---- gemmx: two independent 64-row units (u = tid>>8) ----
    int u = tid512 >> 8, tid = tid512 & 255;
    u32* Au = (u32*)smem + u * 4096;   // 16 KB per unit
    int lane = tid & 63;
    int mt = tid >> 6;
    int r0 = ((blockIdx.x - nsc) * 2 + u) * 64;

    #pragma unroll
    for (int it = 0; it < 16; ++it) {
      int w = it * 256 + tid;
      int row = w >> 6, uu = w & 63;
      int grow = r0 + row;
      float2 v = make_float2(0.f, 0.f);
      if (grow < n) v = *(const float2*)(x + (size_t)grow * FD + uu * 2);
      Au[row * 64 + (uu ^ ((row & 7) << 2))] = (u32)f2bf(v.x) | ((u32)f2bf(v.y) << 16);
    }
    __syncthreads();

    short8 afh[4];
    int arow = mt * 16 + (lane & 15);
    #pragma unroll
    for (int kt = 0; kt < 4; ++kt) {
      int boff = arow * 256 + ((kt * 64 + (lane >> 4) * 16) ^ ((arow & 7) << 4));
      afh[kt] = *(const short8*)((const char*)Au + boff);
    }
    __syncthreads();   // Au dead -> epilogue staging

    for (int nt = 0; nt < 8; ++nt) {
      f32x4 oacc = {0.f, 0.f, 0.f, 0.f};
      #pragma unroll
      for (int kt = 0; kt < 4; ++kt) {
        int f = nt * 4 + kt;
        short8 wh = *(const short8*)(wfhi + (size_t)(f * 64 + lane) * 4);
        short8 wl = *(const short8*)(wflo + (size_t)(f * 64 + lane) * 4);
        oacc = __builtin_amdgcn_mfma_f32_16x16x32_bf16(afh[kt], wh, oacc, 0, 0, 0);
        oacc = __builtin_amdgcn_mfma_f32_16x16x32_bf16(afh[kt], wl, oacc, 0, 0, 0);
      }
      int c = nt * 16 + (lane & 15);
      #pragma unroll
      for (int j = 0; j < 4; ++j) {
        int lrow = mt * 16 + (lane >> 4) * 4 + j;
        ((u16*)Au)[lrow * 128 + c] = f2bf(oacc[j]);   // no bias, no scale
      }
    }
    __syncthreads();
    #pragma unroll
    for (int it = 0; it < 4; ++it) {
      int ci = it * 256 + tid;
      int lrow = ci >> 4, chk = ci & 15;
      int row = r0 + lrow;
      if (row < n)
        *(u32x4*)(tout + (size_t)row * 64 + chk * 4) =
            *(const u32x4*)(Au + lrow * 64 + chk * 4);
    }
    return;
  }

  // ---- scatter (per-block bucket regions; no global cursors) ----
  int* histD = (int*)smem;               // 4 x 128 ints
  int* rankD = histD + NBK;
  int* histS = rankD + NBK;
  int* rankS = histS + NBK;
  u32* stgv = (u32*)(smem + 4096);       // 32 KB (phase A)
  u16* stg2 = (u16*)(smem + 4096);       // 16 KB (phase B, reuses stgv)
  int tid = tid512;
  int blk = blockIdx.x;
  int c0 = blk * CHUNK;
  int total = e + n;
  if (tid < NBK) { histD[tid] = 0; histS[tid] = 0; }
  __syncthreads();
  u32 pv_[NIT]; int bD_[NIT], bS_[NIT]; bool v_[NIT], vs_[NIT];
  #pragma unroll
  for (int i = 0; i < NIT; ++i) {
    int t = c0 + i * ST + tid;
    v_[i] = (t < total);
    vs_[i] = (t < e);
    pv_[i] = 0; bD_[i] = 0; bS_[i] = 0;
    if (v_[i]) {
      int s, d;
      if (vs_[i]) { s = src[t]; d = dst[t]; }
      else        { s = t - e;  d = s; }
      pv_[i] = ((u32)(d & (BNODES - 1)) << 22) | (u32)s;
      bD_[i] = d >> SHIFT;
      atomicAdd(&histD[bD_[i]], 1);
      if (vs_[i]) { bS_[i] = s >> SHIFT; atomicAdd(&histS[bS_[i]], 1); }
    }
  }
  __syncthreads();
  int hD = 0, hS = 0;
  if (tid < NBK) { hD = histD[tid]; hS = histS[tid]; }
  __syncthreads();
  for (int off = 1; off < NBK; off <<= 1) {
    int aD = 0, aS = 0;
    if (tid < NBK && tid >= off) { aD = histD[tid - off]; aS = histS[tid - off]; }
    __syncthreads();
    if (tid < NBK) { histD[tid] += aD; histS[tid] += aS; }
    __syncthreads();
  }
  if (tid < NBK) {
    int exD = histD[tid] - hD;
    int exS = histS[tid] - hS;
    rankD[tid] = exD;
    rankS[tid] = exS;
    ofsD[tid * nsc + blk] = exD;        // per-block bucket offsets
    ofsS[tid * nsc + blk] = exS;
  }
  __syncthreads();
  // phase A: dst-keyed pairs -> linear dump
  #pragma unroll
  for (int i = 0; i < NIT; ++i) {
    if (v_[i]) {
      int p = atomicAdd(&rankD[bD_[i]], 1);
      stgv[p] = pv_[i];
    }
  }
  __syncthreads();
  int V = min(CHUNK, total - c0);
  for (int j = tid; j < V; j += ST)
    pairs[(size_t)blk * CHUNK + j] = stgv[j];      // coalesced, bucket-sorted
  __syncthreads();   // LDS reuse fence
  // phase B: src-keyed pairs2 -> linear dump
  #pragma unroll
  for (int i = 0; i < NIT; ++i) {
    if (vs_[i]) {
      int p = atomicAdd(&rankS[bS_[i]], 1);
      stg2[p] = (u16)(pv_[i] & (BNODES - 1));
    }
  }
  __syncthreads();
  int V2 = min(CHUNK, e - c0);                     // negative -> loop skipped
  for (int j = tid; j < V2; j += ST)
    pairs2[(size_t)blk * CHUNK + j] = stg2[j];
}

// ---------- pass 2: per-bucket finalize from per-block segments ----------
// blocks [0, nbuck): CSR (rp, col, nin).  base(b) = sum_i ofsD[b][i] (global CSR
// offset, since each block's buckets start at 0).  blocks [nbuck, 2*nbuck): nout.
__global__ __launch_bounds__(1024) void k_build(
    const u32* __restrict__ pairs, const u16* __restrict__ pairs2,
    const int* __restrict__ ofsD, const int* __restrict__ ofsS,
    int* __restrict__ rp, int* __restrict__ col,
    float* __restrict__ nin, float* __restrict__ nout,
    int n, int nbuck, int nsc, int total) {
  __shared__ int cnt[BNODES];
  __shared__ int cur[BNODES];
  __shared__ int wsum[16];
  __shared__ int segs[256], sege[256];
  int tid = threadIdx.x;            // 0..1023
  int lane = tid & 63, wv = tid >> 6;

  if (blockIdx.x >= (unsigned)nbuck) {
    // ---- out-degree -> nout ----
    int b = blockIdx.x - nbuck;
    cnt[tid] = 0;
    if (tid < nsc) {
      segs[tid] = tid * CHUNK + ofsS[b * nsc + tid];
      sege[tid] = tid * CHUNK + ofsS[(b + 1) * nsc + tid];
    }
    if (b == 0 && tid == 0) nout[n] = 0.f;   // sentinel for pad gathers
    __syncthreads();
    for (int sg = wv; sg < nsc; sg += 16)
      for (int t = segs[sg] + lane; t < sege[sg]; t += 64)
        atomicAdd(&cnt[(int)pairs2[t]], 1);
    __syncthreads();
    int node = (b << SHIFT) + tid;
    if (node < n) nout[node] = rsqrtf((float)(cnt[tid] + 1));   // +1 self-loop
    return;
  }

  int b = blockIdx.x;
  int node0 = b << SHIFT;
  __shared__ int baseSh;
  cnt[tid] = 0;
  if (tid == 0) baseSh = 0;
  int rowv = 0;
  if (tid < nsc) {
    rowv = ofsD[b * nsc + tid];
    segs[tid] = tid * CHUNK + rowv;
    sege[tid] = tid * CHUNK + ofsD[(b + 1) * nsc + tid];
  }
  __syncthreads();
  if (tid < nsc && rowv) atomicAdd(&baseSh, rowv);   // base = Σ_i ofsD[b][i]
  for (int sg = wv; sg < nsc; sg += 16)
    for (int t = segs[sg] + lane; t < sege[sg]; t += 64)
      atomicAdd(&cnt[(int)(pairs[t] >> 22)], 1);
  __syncthreads();
  int base = baseSh;
  int c = cnt[tid];
  // 2-level inclusive scan: wave shfl scan + 16 wave-sums
  int v = c;
  #pragma unroll
  for (int o = 1; o < 64; o <<= 1) {
    int t = __shfl_up(v, o, 64);
    if (lane >= o) v += t;
  }
  if (lane == 63) wsum[wv] = v;
  __syncthreads();
  if (tid < 16) {
    int w = wsum[tid];
    #pragma unroll
    for (int o = 1; o < 16; o <<= 1) {
      int t = __shfl_up(w, o, 64);
      if (lane >= o) w += t;
    }
    wsum[tid] = w;
  }
  __syncthreads();
  int incl = v + (wv ? wsum[wv - 1] : 0);
  int ex = incl - c;
  int node = node0 + tid;
  if (node < n) {
    rp[node] = base + ex;
    nin[node] = rsqrtf((float)c);              // in-degree incl self-loop
  }
  if (b == nbuck - 1 && tid == 0) rp[n] = total;
  cur[tid] = ex;
  __syncthreads();
  for (int sg = wv; sg < nsc; sg += 16)
    for (int t = segs[sg] + lane; t < sege[sg]; t += 64) {
      u32 pr = pairs[t];
      int p = atomicAdd(&cur[(int)(pr >> 22)], 1);
      col[base + p] = (int)(pr & 0x3FFFFFu);
    }
}

// ---------- gather-aggregate: MODE is compile-time, two clean codegens ----------
// MODE 1: hsout[r] = bf16(nin[r]*sum_s snorm[s]*hs[s] + bias), XOR-swizzled
// MODE 0: fout[r]  = fp32(nin[r]*sum_s hs[s] + bias), plain rows
template <int MODE>
__global__ __launch_bounds__(256) void k_agg(
    const u32* __restrict__ hs, const int* __restrict__ rp,
    const int* __restrict__ col, const float* __restrict__ nin,
    const float* __restrict__ snorm, const float* __restrict__ bias,
    float* __restrict__ fout, u32* __restrict__ hsout, int n) {
  int wid = (blockIdx.x * 256 + threadIdx.x) >> 6;   // global wave id
  int lane = threadIdx.x & 63;
  int g = lane >> 4, ch = lane & 15;
  int r = wid * 4 + g;
  bool valid = (r < n);
  int e0 = 0, e1 = 0;
  if (valid) { e0 = rp[r]; e1 = rp[r + 1]; }   // e1 > e0 (self-loop)
  int m = e1 - e0;
  m = max(m, __shfl_xor(m, 16, 64));
  m = max(m, __shfl_xor(m, 32, 64));
  int trips = (m + 7) >> 3;
  float acc[8] = {0.f, 0.f, 0.f, 0.f, 0.f, 0.f, 0.f, 0.f};
  const u32x4* hv = (const u32x4*)hs;   // 16 chunks per row
  int em1 = (e1 > 0) ? (e1 - 1) : 0;
  for (int it = 0; it < trips; ++it) {
    int tb = e0 + it * 8;
    u32x4 buf[8];
    float wb[8];
    #pragma unroll
    for (int u = 0; u < 8; ++u) {
      int idx = tb + u;
      int s = col[min(idx, em1)];          // group-uniform broadcast load
      s = (idx < e1) ? s : n;              // sentinel zero row for pads
      buf[u] = hv[(size_t)s * 16 + ch];
      if (MODE) wb[u] = snorm[s];          // L2-resident 4B broadcast
    }
    if (MODE) {
      #pragma unroll
      for (int u = 0; u < 8; ++u)
        #pragma unroll
        for (int j = 0; j < 4; ++j) {
          u32 x = buf[u][j];
          acc[2 * j]     = fmaf(__uint_as_float(x << 16), wb[u], acc[2 * j]);
          acc[2 * j + 1] = fmaf(__uint_as_float(x & 0xFFFF0000u), wb[u], acc[2 * j + 1]);
        }
    } else {
      #pragma unroll
      for (int u = 0; u < 8; ++u)
        #pragma unroll
        for (int j = 0; j < 4; ++j) {
          u32 x = buf[u][j];
          acc[2 * j]     += __uint_as_float(x << 16);
          acc[2 * j + 1] += __uint_as_float(x & 0xFFFF0000u);
        }
    }
  }
  if (!valid) return;
  float wi = nin[r];
  float4 b0 = *(const float4*)(bias + ch * 8);
  float4 b1v = *(const float4*)(bias + ch * 8 + 4);
  float v[8];
  v[0] = acc[0] * wi + b0.x;  v[1] = acc[1] * wi + b0.y;
  v[2] = acc[2] * wi + b0.z;  v[3] = acc[3] * wi + b0.w;
  v[4] = acc[4] * wi + b1v.x; v[5] = acc[5] * wi + b1v.y;
  v[6] = acc[6] * wi + b1v.z; v[7] = acc[7] * wi + b1v.w;
  if (MODE == 0) {
    *(float4*)(fout + (size_t)r * FD + ch * 8)     = make_float4(v[0], v[1], v[2], v[3]);
    *(float4*)(fout + (size_t)r * FD + ch * 8 + 4) = make_float4(v[4], v[5], v[6], v[7]);
  } else {
    u32 hi[4];
    #pragma unroll
    for (int j = 0; j < 4; ++j)
      hi[j] = (u32)f2bf(v[2 * j]) | ((u32)f2bf(v[2 * j + 1]) << 16);
    int sch = ch ^ (r & 7);               // 16B-chunk XOR swizzle
    u32x4 hq = {hi[0], hi[1], hi[2], hi[3]};
    *(u32x4*)(hsout + (size_t)r * 64 + sch * 4) = hq;
  }
}

// ---------- Y2 = bf16(nout * (h1 @ W2)): MFMA GEMM, LDS-staged coalesced epi ----------
__global__ __launch_bounds__(256) void k_gemm2(
    const u32* __restrict__ ahi,
    const u32* __restrict__ wfhi, const u32* __restrict__ wflo,
    const float* __restrict__ nout, u32* __restrict__ yout, int n) {
  __shared__ u32 As[4096];   // 16 KB: swizzled input stage, then epi staging
  int tid = threadIdx.x;
  int lane = tid & 63;
  int mt = tid >> 6;
  int r0 = blockIdx.x * 64;

  const u32x4* gh = (const u32x4*)(ahi + (size_t)r0 * 64);
  u32x4* sh_ = (u32x4*)As;
  #pragma unroll
  for (int t = 0; t < 4; ++t) sh_[t * 256 + tid] = gh[t * 256 + tid];
  __syncthreads();

  short8 afh[4];
  int arow = mt * 16 + (lane & 15);
  #pragma unroll
  for (int kt = 0; kt < 4; ++kt) {
    int boff = arow * 256 + ((kt * 64 + (lane >> 4) * 16) ^ ((arow & 7) << 4));
    afh[kt] = *(const short8*)((const char*)As + boff);
  }
  __syncthreads();   // As dead -> reuse for epilogue

  float wout[4];
  #pragma unroll
  for (int j = 0; j < 4; ++j) {
    int row = r0 + mt * 16 + (lane >> 4) * 4 + j;
    wout[j] = (row < n) ? nout[row] : 0.f;
  }

  for (int nt = 0; nt < 8; ++nt) {
    f32x4 oacc = {0.f, 0.f, 0.f, 0.f};
    #pragma unroll
    for (int kt = 0; kt < 4; ++kt) {
      int f = nt * 4 + kt;
      short8 wh = *(const short8*)(wfhi + (size_t)(f * 64 + lane) * 4);
      short8 wl = *(const short8*)(wflo + (size_t)(f * 64 + lane) * 4);
      oacc = __builtin_amdgcn_mfma_f32_16x16x32_bf16(afh[kt], wh, oacc, 0, 0, 0);
      oacc = __builtin_amdgcn_mfma_f32_16x16x32_bf16(afh[kt], wl, oacc, 0, 0, 0);
    }
    int c = nt * 16 + (lane & 15);
    #pragma unroll
    for (int j = 0; j < 4; ++j) {
      int lrow = mt * 16 + (lane >> 4) * 4 + j;
      ((u16*)As)[lrow * 128 + c] = f2bf(oacc[j] * wout[j]);   // no bias here
    }
  }
  __syncthreads();
  #pragma unroll
  for (int it = 0; it < 4; ++it) {
    int ci = it * 256 + tid;
    int lrow = ci >> 4, chk = ci & 15;
    int row = r0 + lrow;
    if (row < n)
      *(u32x4*)(yout + (size_t)row * 64 + chk * 4) =
          *(const u32x4*)(As + lrow * 64 + chk * 4);
  }
}

// ---------------- launch ----------------
extern "C" void kernel_launch(void* const* d_in, const int* in_sizes, int n_in,
                              void* d_out, int out_size, void* d_ws, size_t ws_size,
                              hipStream_t stream) {
  const float* x  = (const float*)d_in[0];
  const int* src  = (const int*)d_in[1];
  const int* dst  = (const int*)d_in[2];
  const float* W1 = (const float*)d_in[3];
  const float* b1 = (const float*)d_in[4];
  const float* W2 = (const float*)d_in[5];
  const float* b2 = (const float*)d_in[6];
  float* out = (float*)d_out;

  int n = in_sizes[0] / FD;      // 100000
  int e = in_sizes[1];           // 1600000
  int total = e + n;
  int nbuck = (n + BNODES - 1) >> SHIFT;   // 98
  int nsc = (total + CHUNK - 1) / CHUNK;   // 208
  int ngx = (n + 127) / 128;               // 782

  char* ws = (char*)d_ws;
  size_t off = 0;
  auto alloc = [&](size_t bytes) -> void* {
    void* p = ws + off;
    off += (bytes + 255) / 256 * 256;
    return p;
  };
  // bufA: T1bf then Y2 (T1 dead after agg1; row n stays 0 from the memset)
  u32* bufA  = (u32*)alloc((size_t)(n + 16) * 64 * 4);     // 25.6 MB
  u32* t1bf  = bufA;
  u32* y2    = bufA;
  u32* pairs = (u32*)alloc((size_t)nsc * CHUNK * 4);       // 6.8 MB
  // bufC: pairs2 (build phase) then h1bf (+64-row pad for gemm2 staging reads)
  u32* bufC  = (u32*)alloc((size_t)(n + 64) * 64 * 4);     // 25.6 MB
  u16* pairs2 = (u16*)bufC;                                // nsc*CHUNK u16 = 3.4 MB
  u32* h1bf  = bufC;
  int* col   = (int*)alloc((size_t)total * 4 + 256);       // 6.8 MB
  int* rp    = (int*)alloc((size_t)(n + 1) * 4);
  float* nin  = (float*)alloc((size_t)n * 4);
  float* nout = (float*)alloc((size_t)(n + 16) * 4);       // +sentinel slot n
  int* ofsD  = (int*)alloc((size_t)NBK * nsc * 4);         // 106 KB
  int* ofsS  = (int*)alloc((size_t)NBK * nsc * 4);         // 106 KB
  u32* wf1hi  = (u32*)alloc(8192 * 4);
  u32* wf1lo  = (u32*)alloc(8192 * 4);
  u32* wf2hi  = (u32*)alloc(8192 * 4);
  u32* wf2lo  = (u32*)alloc(8192 * 4);

  hipMemsetAsync(bufA + (size_t)n * 64, 0, 64 * 4, stream);  // T1/Y2 sentinel row n

  // W-prep FIRST (separate launch: gemmx blocks below consume the planes)
  k_prepw<<<32, 512, 0, stream>>>(W1, wf1hi, wf1lo, W2, wf2hi, wf2lo);
  // scatter ∥ T1 = bf16(X @ W1) — no histogram/scan pre-passes
  k_scatgx<<<nsc + ngx, ST, 0, stream>>>(
      src, dst, pairs, pairs2, ofsD, ofsS, e, n, nbuck, nsc,
      x, wf1hi, wf1lo, t1bf);
  k_build<<<2 * nbuck, 1024, 0, stream>>>(pairs, pairs2, ofsD, ofsS,
                                          rp, col, nin, nout, n, nbuck, nsc, total);

  int agrid = (n + 15) / 16;     // 4 rows/wave, 4 waves/block
  int ggrid = (n + 63) / 64;
  // h1 = bf16(nin * sum_s nout[s]*T1[s] + b1), swizzled for gemm2
  k_agg<1><<<agrid, 256, 0, stream>>>(t1bf, rp, col, nin, nout, b1,
                                      nullptr, h1bf, n);
  // Y2 = bf16(nout * (h1 @ W2))
  k_gemm2<<<ggrid, 256, 0, stream>>>(h1bf, wf2hi, wf2lo, nout, y2, n);
  // out = nin * gather(Y2) + b2   (fp32)
  k_agg<0><<<agrid, 256, 0, stream>>>(y2, rp, col, nin, nullptr, b2,
                                      out, nullptr, n);
}